// Round 7
// baseline (503.069 us; speedup 1.0000x reference)
//
#include <hip/hip_runtime.h>
#include <math.h>

#define HDIM 768
#define HIDD 512
#define NTOK 16384
#define NT 20
#define CHUNKS 128
#define CLEN 128

typedef unsigned short ushort_t;
typedef __attribute__((ext_vector_type(8))) short bf16x8;
typedef __attribute__((ext_vector_type(4))) float f32x4;

__device__ __forceinline__ float sigm(float x){ return 1.0f/(1.0f+expf(-x)); }

__device__ __forceinline__ ushort_t f2bf(float f){
    unsigned int u = __float_as_uint(f);
    unsigned int r = (u + 0x7fffu + ((u >> 16) & 1u)) >> 16;
    return (ushort_t)r;
}
__device__ __forceinline__ float bf2f(ushort_t b){
    return __uint_as_float(((unsigned int)b) << 16);
}

#define GLD16(gp, lp) __builtin_amdgcn_global_load_lds( \
    (const __attribute__((address_space(1))) void*)(gp), \
    (__attribute__((address_space(3))) void*)(lp), 16, 0, 0)

// ---------------------------------------------------------------------------
// conv: blocks [0,1152) pack B (w_ih f/b gates i,g,o) -> Bh/Bl (1536x768);
// blocks [1152,13440) split x rows 1..16384 -> Ah/Al (16384x768).
// ---------------------------------------------------------------------------
__global__ __launch_bounds__(256) void conv_kernel(
    const float* __restrict__ x,
    const float* __restrict__ wf, const float* __restrict__ wb,
    ushort_t* __restrict__ Ah, ushort_t* __restrict__ Al,
    ushort_t* __restrict__ Bh, ushort_t* __restrict__ Bl)
{
    const int bid = blockIdx.x;
    if (bid < 1152){
        int t = bid*256 + threadIdx.x;                 // 1536*192
        int n = t / 192, c4 = (t - n*192)*4;
        int dir = n / 768, nr = n - dir*768;
        int gate = nr >> 8, j = nr & 255;
        int wrow = j + ((gate==0)?0:((gate==1)?512:768));
        const float* src = dir ? wb : wf;
        const float4 v = *(const float4*)(src + (size_t)wrow*HDIM + c4);
        float f[4] = {v.x, v.y, v.z, v.w};
        ushort_t h[4], l[4];
        #pragma unroll
        for (int i=0;i<4;++i){
            h[i] = f2bf(f[i]);
            l[i] = f2bf(f[i] - bf2f(h[i]));
        }
        *(ushort4*)(Bh + (size_t)n*HDIM + c4) = make_ushort4(h[0],h[1],h[2],h[3]);
        *(ushort4*)(Bl + (size_t)n*HDIM + c4) = make_ushort4(l[0],l[1],l[2],l[3]);
    } else {
        int t = (bid-1152)*256 + threadIdx.x;          // 16384*192
        int row = t / 192, c4 = (t - row*192)*4;
        const float4 v = *(const float4*)(x + (size_t)(row+1)*HDIM + c4);
        float f[4] = {v.x, v.y, v.z, v.w};
        ushort_t h[4], l[4];
        #pragma unroll
        for (int i=0;i<4;++i){
            h[i] = f2bf(f[i]);
            l[i] = f2bf(f[i] - bf2f(h[i]));
        }
        *(ushort4*)(Ah + (size_t)row*HDIM + c4) = make_ushort4(h[0],h[1],h[2],h[3]);
        *(ushort4*)(Al + (size_t)row*HDIM + c4) = make_ushort4(l[0],l[1],l[2],l[3]);
    }
}

// ---------------------------------------------------------------------------
// Split-bf16 MFMA GEMM, R7: B direct-to-register.
//
// Diagnosis: 5 schedule variants (R0-R4) all pinned at ~134 us / MfmaUtil
// ~38 because per-kt LDS traffic (160 KB read + 64 KB written per CU,
// ~2400 cyc) rivals MFMA (~2794 cyc) and they serialize; every schedule
// conserved LDS traffic -> all null. R7 REMOVES B from LDS: per-wave B
// fragments are wave-private (only the wm-twin shares -> L1 serves it),
// loaded as per-lane global_load_dwordx4 with a full kt (~3000 cyc) of
// latency cover, double-buffered by kt parity (bsA/bsB, static names).
// LDS per kt drops to A only (64 KB read, 16 KB written, ~900 cyc << MFMA).
// One barrier + one vmcnt(0) per kt (all loads have full-kt cover).
// Hazards: A(kt) frags read right after barrier (GLD16 from kt-1 drained by
// vmcnt(0); barrier => all waves' prior-buffer reads retired before the
// next GLD16 write to it). B regs carry compiler data-dep waits.
// B values identical, per-acc MFMA order (kt 0..23; hh,lh,hl) identical,
// epilogue identical -> bit-identical gates/feats (absmax 0.0 preserved).
// LDS 43.5 KB, 8 waves, ~230 VGPR target (2 waves/SIMD). Tripwire: if
// WRITE_SIZE jumps above ~10240 KB, register spill -> revert.
// ---------------------------------------------------------------------------
#define VMCNT(n) asm volatile("s_waitcnt vmcnt(" #n ")" ::: "memory")
#define BARRIER() asm volatile("s_barrier" ::: "memory")

#define LOADB(S, KT) do{                                                      \
  _Pragma("unroll")                                                           \
  for (int g=0; g<3; ++g)                                                     \
    _Pragma("unroll")                                                         \
    for (int f=0; f<2; ++f){                                                  \
      bs##S[g*4+f*2+0] = *(const bf16x8*)((const char*)Bh + bByte[g][f] + (KT)*64); \
      bs##S[g*4+f*2+1] = *(const bf16x8*)((const char*)Bl + bByte[g][f] + (KT)*64); \
    }                                                                         \
}while(0)

#define READ_A(ab) do{ _Pragma("unroll") for (int f=0; f<4; ++f){             \
    aH[f] = *(const bf16x8*)((ab) + aoffB[f]);                                \
    aL[f] = *(const bf16x8*)((ab) + 8192 + aoffB[f]); } }while(0)

// per-acc order (hh, lh, hl) identical to prior rounds -> bit-exact
#define MFMA_CLUSTER(g, S) do{                                                \
  __builtin_amdgcn_sched_barrier(0);                                          \
  __builtin_amdgcn_s_setprio(1);                                              \
  _Pragma("unroll")                                                           \
  for (int fn=0; fn<2; ++fn){                                                 \
    _Pragma("unroll")                                                         \
    for (int fm=0; fm<4; ++fm){                                               \
      acc[g][fm][fn] = __builtin_amdgcn_mfma_f32_16x16x32_bf16(aH[fm],        \
          bs##S[(g)*4+fn*2], acc[g][fm][fn], 0, 0, 0);                        \
      acc[g][fm][fn] = __builtin_amdgcn_mfma_f32_16x16x32_bf16(aL[fm],        \
          bs##S[(g)*4+fn*2], acc[g][fm][fn], 0, 0, 0);                        \
      acc[g][fm][fn] = __builtin_amdgcn_mfma_f32_16x16x32_bf16(aH[fm],        \
          bs##S[(g)*4+fn*2+1], acc[g][fm][fn], 0, 0, 0);                      \
    }                                                                         \
  }                                                                           \
  __builtin_amdgcn_s_setprio(0);                                              \
  __builtin_amdgcn_sched_barrier(0);                                          \
}while(0)

// P = kt parity (LDS buf), CUR/NXT = B register set names
#define KT_BODY(KT, P, CUR, NXT) do{                                          \
    VMCNT(0); BARRIER();                                                      \
    READ_A(smem + (P)*16384);                                                 \
    LOADB(NXT, (KT)+1);                                                       \
    GLD16(Ah + gA + ((KT)+1)*32, smem + (1-(P))*16384 + wbB);                 \
    GLD16(Al + gA + ((KT)+1)*32, smem + (1-(P))*16384 + 8192 + wbB);          \
    MFMA_CLUSTER(0, CUR);                                                     \
    MFMA_CLUSTER(1, CUR);                                                     \
    MFMA_CLUSTER(2, CUR);                                                     \
}while(0)

__global__ __launch_bounds__(512, 2) void gemm_fused(
    const ushort_t* __restrict__ Ah, const ushort_t* __restrict__ Al,
    const ushort_t* __restrict__ Bh, const ushort_t* __restrict__ Bl,
    const float* __restrict__ bihf, const float* __restrict__ bhhf,
    const float* __restrict__ bihb, const float* __restrict__ bhhb,
    const float* __restrict__ wtag, float* __restrict__ featsp)
{
    __shared__ __align__(16) char smem[43520];
    // loop: A buf P at P*16384 (Ah 8K @0, Al 8K @8192), dbuf = 32 KB.
    // epilogue reuse: hbuf 128x65 f32 @0, wts 2x20x64 f32 @33280.
    float* hbuf = (float*)smem;
    float* wts  = (float*)(smem + 33280);

    const int tid = threadIdx.x;
    const int bx = blockIdx.x;
    const int xcd = bx & 7, g3 = bx >> 3;
    const int qb = g3 & 3, mt = (g3 >> 2)*8 + xcd;       // 4 qb share XCD
    const int dir = qb >> 1, jhalf = qb & 1;
    const int j0 = jhalf*128;
    const int row0 = mt*128;
    const float* __restrict__ bih = dir ? bihb : bihf;
    const float* __restrict__ bhh = dir ? bhhb : bhhf;

    const int lane = tid & 63, wv = tid >> 6;            // 8 waves
    const int wm = wv >> 2, wn = wv & 3;                 // 2m x 4n
    const int lm = lane & 15, lq = lane >> 4;
    const int wbB = (tid & 448) * 16;                    // wave-uniform byte base

    // ---- A staging decode: slot tid -> (row 0..127, k8) under pair swizzle
    const int P_ = tid >> 3, s_ = tid & 7;
    const int q_ = s_ ^ (P_ & 7);
    const int mA = (P_ << 1) | (q_ >> 2);                // 0..127
    const int k8s = q_ & 3;
    const size_t gA  = (size_t)(row0 + mA)*HDIM + k8s*8;

    // ---- A fragment ds_read byte offsets ----------------------------------
    int aoffB[4];
    #pragma unroll
    for (int f=0; f<4; ++f){
        int m = wm*64 + f*16 + lm;                       // 0..127
        int rg = m >> 6, r = m & 63;
        aoffB[f] = rg*4096 + ((r>>1)*8 + ((((r&1)<<2)|lq) ^ ((r>>1)&7)))*16;
    }

    // ---- B per-lane global byte offsets (row*1536 + lq*16; +kt*64 later) --
    int bByte[3][2];
    #pragma unroll
    for (int g=0; g<3; ++g)
        #pragma unroll
        for (int f=0; f<2; ++f)
            bByte[g][f] = (dir*768 + g*256 + j0 + wn*32 + f*16 + lm)*(HDIM*2)
                          + lq*16;

    f32x4 acc[3][4][2];                                  // [gate][fm][fn]
    #pragma unroll
    for (int g=0; g<3; ++g)
        #pragma unroll
        for (int fm=0; fm<4; ++fm)
            #pragma unroll
            for (int fn=0; fn<2; ++fn)
                acc[g][fm][fn] = (f32x4){0.f,0.f,0.f,0.f};

    bf16x8 aH[4], aL[4];                                 // A frags (per kt)
    bf16x8 bsA[12], bsB[12];                             // B dbuf by kt parity

    // ---- prologue: B(0) -> set A; A(0) -> buf0 ----------------------------
    LOADB(A, 0);
    GLD16(Ah + gA, smem + wbB);
    GLD16(Al + gA, smem + 8192 + wbB);

    #pragma unroll 1
    for (int kt2 = 0; kt2 < 11; ++kt2){
        KT_BODY(2*kt2,   0, A, B);
        KT_BODY(2*kt2+1, 1, B, A);
    }
    KT_BODY(22, 0, A, B);

    // ---- peeled kt=23 (P=1, set B): no further loads ----------------------
    {
        VMCNT(0); BARRIER();
        READ_A(smem + 16384);
        MFMA_CLUSTER(0, B);
        MFMA_CLUSTER(1, B);
        MFMA_CLUSTER(2, B);
    }

    // ---- epilogue: gates -> h -> partial feats ----------------------------
    int jcol[2];
    #pragma unroll
    for (int f=0; f<2; ++f) jcol[f] = j0 + wn*32 + f*16 + lm;   // 0..255

    float bi[2], bg_[2], bo[2];
    #pragma unroll
    for (int f=0; f<2; ++f){
        bi[f]  = bih[jcol[f]]       + bhh[jcol[f]];
        bg_[f] = bih[512 + jcol[f]] + bhh[512 + jcol[f]];
        bo[f]  = bih[768 + jcol[f]] + bhh[768 + jcol[f]];
    }
    float hv[4][2][4];
    #pragma unroll
    for (int fm=0; fm<4; ++fm)
        #pragma unroll
        for (int fn=0; fn<2; ++fn)
            #pragma unroll
            for (int r=0; r<4; ++r){
                float cv = sigm(acc[0][fm][fn][r] + bi[fn]) *
                           tanhf(acc[1][fm][fn][r] + bg_[fn]);
                hv[fm][fn][r] = sigm(acc[2][fm][fn][r] + bo[fn]) * tanhf(cv);
            }

    __syncthreads();   // all K-loop LDS reads done before smem reuse
    // wts[cc][t][j]: wtag slice for the two 64-col chunks of this block
    for (int idx=tid; idx<2*NT*64; idx+=512){
        int cc = idx / (NT*64), r = idx - cc*(NT*64);
        int t = r >> 6, j = r & 63;
        wts[idx] = wtag[t*HIDD + dir*256 + j0 + cc*64 + j];
    }
    #pragma unroll 1
    for (int cc=0; cc<2; ++cc){
        __syncthreads();
        if ((wn >> 1) == cc){
            #pragma unroll
            for (int fm=0; fm<4; ++fm)
                #pragma unroll
                for (int fn=0; fn<2; ++fn)
                    #pragma unroll
                    for (int r=0; r<4; ++r){
                        int mloc = wm*64 + fm*16 + lq*4 + r;    // 0..127
                        int jloc = (wn&1)*32 + fn*16 + lm;      // 0..63
                        hbuf[mloc*65 + jloc] = hv[fm][fn][r];
                    }
        }
        __syncthreads();
        // same 64-long fmaf chain per (row, chunk, tag) as prior rounds
        const int mrow = tid & 127, grp = tid >> 7;             // 4 grp x 5 tags
        const int tg0 = grp*5;
        const float* wc = wts + cc*(NT*64);
        float s[5] = {0.f,0.f,0.f,0.f,0.f};
        for (int j=0;j<64;++j){
            float h = hbuf[mrow*65 + j];
            #pragma unroll
            for (int tt=0; tt<5; ++tt)
                s[tt] = fmaf(h, wc[(tg0+tt)*64 + j], s[tt]);
        }
        const int p = dir*4 + jhalf*2 + cc;                     // partial idx
        float* fq = featsp + (size_t)p * (NTOK*NT);
        const int mglob = row0 + mrow;
        #pragma unroll
        for (int tt=0; tt<5; ++tt)
            fq[(size_t)mglob*NT + tg0 + tt] = s[tt];
    }
}

// ---------------------------------------------------------------------------
// fl loader: identical deterministic sum of the 8 partial buffers + btag.
// ---------------------------------------------------------------------------
__device__ __forceinline__ void load_fl(
    const float* __restrict__ featsp, const float* __restrict__ btg,
    float* fl, int c, int tid, int nthr)
{
    const int base = c*(CLEN*NT/4);
    for (int idx=tid; idx<CLEN*NT/4; idx+=nthr){
        float4 s[8];
        #pragma unroll
        for (int p=0; p<8; ++p)
            s[p] = ((const float4*)(featsp + (size_t)p*NTOK*NT))[base+idx];
        float4 v;
        v.x = ((s[0].x+s[1].x)+(s[2].x+s[3].x)) + ((s[4].x+s[5].x)+(s[6].x+s[7].x));
        v.y = ((s[0].y+s[1].y)+(s[2].y+s[3].y)) + ((s[4].y+s[5].y)+(s[6].y+s[7].y));
        v.z = ((s[0].z+s[1].z)+(s[2].z+s[3].z)) + ((s[4].z+s[5].z)+(s[6].z+s[7].z));
        v.w = ((s[0].w+s[1].w)+(s[2].w+s[3].w)) + ((s[4].w+s[5].w)+(s[6].w+s[7].w));
        int t0 = (idx*4) % 20;
        v.x += btg[t0]; v.y += btg[t0+1]; v.z += btg[t0+2]; v.w += btg[t0+3];
        ((float4*)fl)[idx] = v;
    }
}

// ---------------------------------------------------------------------------
// V1 (R6 layout kept): per-chunk max-plus matrix product, transposed LDS
// (Pt[j][k], stride 24) -> column read = 5x ds_read_b128; thread = (j, row
// pair). Arithmetic bit-identical to the original (same seed, ascending-k
// fmaxf chain, same output mapping).
// ---------------------------------------------------------------------------
__global__ __launch_bounds__(256) void vit_chunkmat(
    const float* __restrict__ featsp, const float* __restrict__ btag,
    const float* __restrict__ trans, float* __restrict__ Pall)
{
    __shared__ float fl[CLEN*NT];
    __shared__ float Pt[2][NT*24];          // transposed, padded stride 24
    const int c = blockIdx.x, tid = threadIdx.x;
    load_fl(featsp, btag, fl, c, tid, 256);
    const bool act = tid < 200;
    const int j = tid / 10, ip = tid - j*10;
    const int ia = ip*2, ib = ia + 1;
    float tra[NT], trb[NT];
    if (act){
        #pragma unroll
        for (int k=0;k<NT;++k){
            tra[k] = trans[ia*NT+k];
            trb[k] = trans[ib*NT+k];
        }
        Pt[0][j*24+ia] = (ia==j) ? 0.f : -1e30f;
        Pt[0][j*24+ib] = (ib==j) ? 0.f : -1e30f;
    }
    __syncthreads();
    int cur = 0;
    #pragma unroll 1
    for (int t=0;t<CLEN;++t){
        if (act){
            float p[NT];
            #pragma unroll
            for (int q=0;q<5;++q){
                float4 v = *(const float4*)&Pt[cur][j*24 + q*4];
                p[q*4+0]=v.x; p[q*4+1]=v.y; p[q*4+2]=v.z; p[q*4+3]=v.w;
            }
            float ma = -3.0e38f, mb = -3.0e38f;
            #pragma unroll
            for (int k=0;k<NT;++k){
                ma = fmaxf(ma, tra[k] + p[k]);      // same chain order as before
                mb = fmaxf(mb, trb[k] + p[k]);
            }
            ma += fl[t*NT+ia];
            mb += fl[t*NT+ib];
            Pt[cur^1][j*24+ia] = ma;
            Pt[cur^1][j*24+ib] = mb;
        }
        __syncthreads();
        cur ^= 1;
    }
    if (act){
        Pall[(size_t)c*(NT*NT) + ia*NT + j] = Pt[cur][j*24+ia];
        Pall[(size_t)c*(NT*NT) + ib*NT + j] = Pt[cur][j*24+ib];
    }
}

// ---------------------------------------------------------------------------
// V2: sequential chunk scan -> fv at chunk starts + terminal argmax/score.
// ---------------------------------------------------------------------------
__global__ __launch_bounds__(128) void vit_scan(
    const float* __restrict__ Pall, const float* __restrict__ trans,
    float* __restrict__ fvstart, float* __restrict__ dout, int* __restrict__ bestws)
{
    __shared__ float Pb[NT*NT];
    __shared__ float fv[NT];
    const int tid = threadIdx.x;
    float4 pn = {0.f,0.f,0.f,0.f};
    if (tid<100) pn = ((const float4*)Pall)[tid];
    if (tid<NT) fv[tid] = (tid==18) ? 0.f : -10000.f;   // START=18
    for (int c=0;c<CHUNKS;++c){
        if (tid<100) ((float4*)Pb)[tid] = pn;
        if (tid<100 && c+1<CHUNKS) pn = ((const float4*)(Pall + (size_t)(c+1)*(NT*NT)))[tid];
        __syncthreads();
        if (tid<NT) fvstart[c*NT+tid] = fv[tid];
        float nf = -3.0e38f;
        if (tid<NT){
            #pragma unroll
            for (int j=0;j<NT;++j) nf = fmaxf(nf, Pb[tid*NT+j] + fv[j]);
        }
        __syncthreads();
        if (tid<NT) fv[tid] = nf;
    }
    __syncthreads();
    if (tid==0){
        float best = -3.0e38f; int bidx = 0;
        for (int j=0;j<NT;++j){
            float tv = fv[j] + trans[19*NT+j];          // STOP row = 19
            if (tv > best){ best = tv; bidx = j; }
        }
        dout[0] = best;
        bestws[0] = bidx;
    }
}

// ---------------------------------------------------------------------------
// V3: exact per-step replay (reference argmax semantics) -> backpointers + H_c
// ---------------------------------------------------------------------------
__global__ __launch_bounds__(128) void vit_replay(
    const float* __restrict__ featsp, const float* __restrict__ btag,
    const float* __restrict__ trans, const float* __restrict__ fvstart,
    unsigned int* __restrict__ bpout, int* __restrict__ Hout)
{
    __shared__ float fl[CLEN*NT];
    __shared__ float fv[NT];
    __shared__ unsigned char bp[CLEN*NT];
    const int c = blockIdx.x, tid = threadIdx.x;
    load_fl(featsp, btag, fl, c, tid, 128);
    float tr[NT];
    if (tid<NT){
        fv[tid] = fvstart[c*NT+tid];
        #pragma unroll
        for (int k=0;k<NT;++k) tr[k] = trans[tid*NT+k];
    }
    __syncthreads();
    for (int t=0;t<CLEN;++t){
        float best = 0.f; int bj = 0;
        if (tid<NT){
            best = tr[0] + fv[0];
            #pragma unroll
            for (int j=1;j<NT;++j){
                float v = tr[j] + fv[j];
                if (v > best){ best = v; bj = j; }      // strict > == first-win
            }
        }
        __syncthreads();
        if (tid<NT){
            fv[tid] = best + fl[t*NT+tid];
            bp[t*NT+tid] = (unsigned char)bj;
        }
        __syncthreads();
    }
    for (int idx=tid; idx<CLEN*NT/4; idx+=128)
        bpout[(size_t)c*(CLEN*NT/4) + idx] = ((unsigned int*)bp)[idx];
    if (tid<NT){
        int m = tid;
        for (int t=CLEN-1;t>=0;--t) m = bp[t*NT+m];
        Hout[c*NT+tid] = m;
    }
}

// ---------------------------------------------------------------------------
// V4: each block walks the composed chunk maps from bestws down to its own
// chunk, then backtracks its chunk and writes the path slice.
// ---------------------------------------------------------------------------
__global__ __launch_bounds__(64) void bt_fill(
    const unsigned int* __restrict__ bpin, const int* __restrict__ Hin,
    const int* __restrict__ bestws, float* __restrict__ dout)
{
    __shared__ int Hl[CHUNKS*NT];
    __shared__ unsigned char bp[CLEN*NT];
    __shared__ float ob[CLEN];
    const int c = blockIdx.x, tid = threadIdx.x;
    for (int idx=tid; idx<CHUNKS*NT; idx+=64) Hl[idx] = Hin[idx];
    for (int idx=tid; idx<CLEN*NT/4; idx+=64)
        ((unsigned int*)bp)[idx] = bpin[(size_t)c*(CLEN*NT/4) + idx];
    __syncthreads();
    if (tid==0){
        int e = bestws[0];
        for (int cc=CHUNKS-1; cc>c; --cc) e = Hl[cc*NT+e];
        for (int t=CLEN-1;t>=0;--t){ ob[t] = (float)e; e = bp[t*NT+e]; }
    }
    __syncthreads();
    for (int idx=tid; idx<CLEN; idx+=64)
        dout[1 + c*CLEN + idx] = ob[idx];
}

// ---------------------------------------------------------------------------
extern "C" void kernel_launch(void* const* d_in, const int* in_sizes, int n_in,
                              void* d_out, int out_size, void* d_ws, size_t ws_size,
                              hipStream_t stream)
{
    const float* x    = (const float*)d_in[0];
    const float* wf   = (const float*)d_in[1];
    const float* bihf = (const float*)d_in[3];
    const float* bhhf = (const float*)d_in[4];
    const float* wb   = (const float*)d_in[5];
    const float* bihb = (const float*)d_in[7];
    const float* bhhb = (const float*)d_in[8];
    const float* wtag = (const float*)d_in[9];
    const float* btag = (const float*)d_in[10];
    const float* trans= (const float*)d_in[11];
    float* out = (float*)d_out;

    char* w = (char*)d_ws;
    ushort_t* Ah = (ushort_t*)w;         w += 25165824;   // 16384*768*2
    ushort_t* Al = (ushort_t*)w;         w += 25165824;
    ushort_t* Bh = (ushort_t*)w;         w += 2359296;    // 1536*768*2
    ushort_t* Bl = (ushort_t*)w;         w += 2359296;
    float* featsp = (float*)w;           w += 10485760;   // 8 * 16384*20 * 4B
    float* Pall  = (float*)w;            w += 204800;     // 128*400*4
    float* fvst  = (float*)w;            w += 10240;      // 128*20*4
    int* Hmap    = (int*)w;              w += 10240;      // 128*20*4
    unsigned int* bp = (unsigned int*)w; w += 327680;     // 16384*20 bytes
    int* best    = (int*)w;

    conv_kernel<<<13440, 256, 0, stream>>>(x, wf, wb, Ah, Al, Bh, Bl);
    gemm_fused<<<512, 512, 0, stream>>>(Ah, Al, Bh, Bl, bihf, bhhf, bihb, bhhb,
                                        wtag, featsp);
    vit_chunkmat<<<CHUNKS, 256, 0, stream>>>(featsp, btag, trans, Pall);
    vit_scan<<<1, 128, 0, stream>>>(Pall, trans, fvst, out, best);
    vit_replay<<<CHUNKS, 128, 0, stream>>>(featsp, btag, trans, fvst, bp, Hmap);
    bt_fill<<<CHUNKS, 64, 0, stream>>>(bp, Hmap, best, out);
}

// Round 8
// 428.603 us; speedup vs baseline: 1.1737x; 1.1737x over previous
//
#include <hip/hip_runtime.h>
#include <math.h>

#define HDIM 768
#define HIDD 512
#define NTOK 16384
#define NT 20
#define CHUNKS 128
#define CLEN 128

typedef unsigned short ushort_t;
typedef __attribute__((ext_vector_type(8))) short bf16x8;
typedef __attribute__((ext_vector_type(4))) float f32x4;

__device__ __forceinline__ float sigm(float x){ return 1.0f/(1.0f+expf(-x)); }

__device__ __forceinline__ ushort_t f2bf(float f){
    unsigned int u = __float_as_uint(f);
    unsigned int r = (u + 0x7fffu + ((u >> 16) & 1u)) >> 16;
    return (ushort_t)r;
}
__device__ __forceinline__ float bf2f(ushort_t b){
    return __uint_as_float(((unsigned int)b) << 16);
}

#define GLD16(gp, lp) __builtin_amdgcn_global_load_lds( \
    (const __attribute__((address_space(1))) void*)(gp), \
    (__attribute__((address_space(3))) void*)(lp), 16, 0, 0)

// ---------------------------------------------------------------------------
// conv: blocks [0,1152) pack B (w_ih f/b gates i,g,o) -> Bh/Bl (1536x768);
// blocks [1152,13440) split x rows 1..16384 -> Ah/Al (16384x768).
// ---------------------------------------------------------------------------
__global__ __launch_bounds__(256) void conv_kernel(
    const float* __restrict__ x,
    const float* __restrict__ wf, const float* __restrict__ wb,
    ushort_t* __restrict__ Ah, ushort_t* __restrict__ Al,
    ushort_t* __restrict__ Bh, ushort_t* __restrict__ Bl)
{
    const int bid = blockIdx.x;
    if (bid < 1152){
        int t = bid*256 + threadIdx.x;                 // 1536*192
        int n = t / 192, c4 = (t - n*192)*4;
        int dir = n / 768, nr = n - dir*768;
        int gate = nr >> 8, j = nr & 255;
        int wrow = j + ((gate==0)?0:((gate==1)?512:768));
        const float* src = dir ? wb : wf;
        const float4 v = *(const float4*)(src + (size_t)wrow*HDIM + c4);
        float f[4] = {v.x, v.y, v.z, v.w};
        ushort_t h[4], l[4];
        #pragma unroll
        for (int i=0;i<4;++i){
            h[i] = f2bf(f[i]);
            l[i] = f2bf(f[i] - bf2f(h[i]));
        }
        *(ushort4*)(Bh + (size_t)n*HDIM + c4) = make_ushort4(h[0],h[1],h[2],h[3]);
        *(ushort4*)(Bl + (size_t)n*HDIM + c4) = make_ushort4(l[0],l[1],l[2],l[3]);
    } else {
        int t = (bid-1152)*256 + threadIdx.x;          // 16384*192
        int row = t / 192, c4 = (t - row*192)*4;
        const float4 v = *(const float4*)(x + (size_t)(row+1)*HDIM + c4);
        float f[4] = {v.x, v.y, v.z, v.w};
        ushort_t h[4], l[4];
        #pragma unroll
        for (int i=0;i<4;++i){
            h[i] = f2bf(f[i]);
            l[i] = f2bf(f[i] - bf2f(h[i]));
        }
        *(ushort4*)(Ah + (size_t)row*HDIM + c4) = make_ushort4(h[0],h[1],h[2],h[3]);
        *(ushort4*)(Al + (size_t)row*HDIM + c4) = make_ushort4(l[0],l[1],l[2],l[3]);
    }
}

// ---------------------------------------------------------------------------
// Split-bf16 MFMA GEMM, R8: B direct-to-register, budget-fitted.
//
// R7 confirmed the plumbing but spilled: launch_bounds(512,2) resolved to a
// 128-VGPR cap while 24 in-flight B frags needed ~260 -> 40 MB scratch
// (WRITE_SIZE 51200). R8: (1) launch_bounds(512,1) -> 256-VGPR cap (1
// block/CU -- same occupancy we had anyway); (2) B in-flight halved to 12
// frags: three fixed per-gate sets (bsA=g0, bsB=g1, bsC=g2), JIT-pipelined
// one gate ahead -- each B load covered by one ~250-cyc MFMA cluster vs
// L1/L2 latency. Budget: acc96 + A32 + B48 + addr ~25 = ~200 < 256.
// Per-kt LDS traffic is now A only (~830 cyc/CU << MFMA 2794 cyc).
//   issue order per kt: setB=g1(kt)[4], GLD16 A(kt+1)[2], setC=g2(kt)[4],
//                       setA=g0(kt+1)[4]
//   kt-top vmcnt: newer-than-GLD16(A(kt)) = setC+setA' = 8 -> VMCNT(8)
//   (kt=0: VMCNT(0) prologue drain; kt=23 tail: VMCNT(4)).
// B consumption waits are compiler data-dep vmcnt. Race ledger: each wave's
// A-frag ds_reads retire before its g0 cluster; buffer rewritten only after
// the next kt-top barrier -> no cross-wave hazard. B values identical,
// per-acc MFMA order (kt 0..23; hh,lh,hl) identical, epilogue identical ->
// bit-identical gates/feats. Tripwire: WRITE_SIZE >~ 12 MB = spill, revert.
// ---------------------------------------------------------------------------
#define VMCNT(n) asm volatile("s_waitcnt vmcnt(" #n ")" ::: "memory")
#define BARRIER() asm volatile("s_barrier" ::: "memory")

#define LOADB_SET(S, g, KT) do{                                               \
    bs##S[0] = *(const bf16x8*)((const char*)Bh + bByte[g][0] + (KT)*64);     \
    bs##S[1] = *(const bf16x8*)((const char*)Bl + bByte[g][0] + (KT)*64);     \
    bs##S[2] = *(const bf16x8*)((const char*)Bh + bByte[g][1] + (KT)*64);     \
    bs##S[3] = *(const bf16x8*)((const char*)Bl + bByte[g][1] + (KT)*64);     \
}while(0)

#define READ_A(ab) do{ _Pragma("unroll") for (int f=0; f<4; ++f){             \
    aH[f] = *(const bf16x8*)((ab) + aoffB[f]);                                \
    aL[f] = *(const bf16x8*)((ab) + 8192 + aoffB[f]); } }while(0)

// per-acc order (hh, lh, hl) identical to prior rounds -> bit-exact
#define MFMA_CLUSTER(g, S) do{                                                \
  __builtin_amdgcn_sched_barrier(0);                                          \
  __builtin_amdgcn_s_setprio(1);                                              \
  _Pragma("unroll")                                                           \
  for (int fn=0; fn<2; ++fn){                                                 \
    _Pragma("unroll")                                                         \
    for (int fm=0; fm<4; ++fm){                                               \
      acc[g][fm][fn] = __builtin_amdgcn_mfma_f32_16x16x32_bf16(aH[fm],        \
          bs##S[fn*2], acc[g][fm][fn], 0, 0, 0);                              \
      acc[g][fm][fn] = __builtin_amdgcn_mfma_f32_16x16x32_bf16(aL[fm],        \
          bs##S[fn*2], acc[g][fm][fn], 0, 0, 0);                              \
      acc[g][fm][fn] = __builtin_amdgcn_mfma_f32_16x16x32_bf16(aH[fm],        \
          bs##S[fn*2+1], acc[g][fm][fn], 0, 0, 0);                            \
    }                                                                         \
  }                                                                           \
  __builtin_amdgcn_s_setprio(0);                                              \
  __builtin_amdgcn_sched_barrier(0);                                          \
}while(0)

// P = kt parity (LDS buf); VM = kt-top vmcnt
#define KT_BODY(KT, P, VM) do{                                                \
    VMCNT(VM); BARRIER();                                                     \
    READ_A(smem + (P)*16384);                                                 \
    LOADB_SET(B, 1, KT);                                                      \
    GLD16(Ah + gA + ((KT)+1)*32, smem + (1-(P))*16384 + wbB);                 \
    GLD16(Al + gA + ((KT)+1)*32, smem + (1-(P))*16384 + 8192 + wbB);          \
    MFMA_CLUSTER(0, A);                                                       \
    LOADB_SET(C, 2, KT);                                                      \
    MFMA_CLUSTER(1, B);                                                       \
    LOADB_SET(A, 0, (KT)+1);                                                  \
    MFMA_CLUSTER(2, C);                                                       \
}while(0)

__global__ __launch_bounds__(512, 1) void gemm_fused(
    const ushort_t* __restrict__ Ah, const ushort_t* __restrict__ Al,
    const ushort_t* __restrict__ Bh, const ushort_t* __restrict__ Bl,
    const float* __restrict__ bihf, const float* __restrict__ bhhf,
    const float* __restrict__ bihb, const float* __restrict__ bhhb,
    const float* __restrict__ wtag, float* __restrict__ featsp)
{
    __shared__ __align__(16) char smem[43520];
    // loop: A buf P at P*16384 (Ah 8K @0, Al 8K @8192), dbuf = 32 KB.
    // epilogue reuse: hbuf 128x65 f32 @0, wts 2x20x64 f32 @33280.
    float* hbuf = (float*)smem;
    float* wts  = (float*)(smem + 33280);

    const int tid = threadIdx.x;
    const int bx = blockIdx.x;
    const int xcd = bx & 7, g3 = bx >> 3;
    const int qb = g3 & 3, mt = (g3 >> 2)*8 + xcd;       // 4 qb share XCD
    const int dir = qb >> 1, jhalf = qb & 1;
    const int j0 = jhalf*128;
    const int row0 = mt*128;
    const float* __restrict__ bih = dir ? bihb : bihf;
    const float* __restrict__ bhh = dir ? bhhb : bhhf;

    const int lane = tid & 63, wv = tid >> 6;            // 8 waves
    const int wm = wv >> 2, wn = wv & 3;                 // 2m x 4n
    const int lm = lane & 15, lq = lane >> 4;
    const int wbB = (tid & 448) * 16;                    // wave-uniform byte base

    // ---- A staging decode: slot tid -> (row 0..127, k8) under pair swizzle
    const int P_ = tid >> 3, s_ = tid & 7;
    const int q_ = s_ ^ (P_ & 7);
    const int mA = (P_ << 1) | (q_ >> 2);                // 0..127
    const int k8s = q_ & 3;
    const size_t gA  = (size_t)(row0 + mA)*HDIM + k8s*8;

    // ---- A fragment ds_read byte offsets ----------------------------------
    int aoffB[4];
    #pragma unroll
    for (int f=0; f<4; ++f){
        int m = wm*64 + f*16 + lm;                       // 0..127
        int rg = m >> 6, r = m & 63;
        aoffB[f] = rg*4096 + ((r>>1)*8 + ((((r&1)<<2)|lq) ^ ((r>>1)&7)))*16;
    }

    // ---- B per-lane global byte offsets (row*1536 + lq*16; +kt*64 later) --
    int bByte[3][2];
    #pragma unroll
    for (int g=0; g<3; ++g)
        #pragma unroll
        for (int f=0; f<2; ++f)
            bByte[g][f] = (dir*768 + g*256 + j0 + wn*32 + f*16 + lm)*(HDIM*2)
                          + lq*16;

    f32x4 acc[3][4][2];                                  // [gate][fm][fn]
    #pragma unroll
    for (int g=0; g<3; ++g)
        #pragma unroll
        for (int fm=0; fm<4; ++fm)
            #pragma unroll
            for (int fn=0; fn<2; ++fn)
                acc[g][fm][fn] = (f32x4){0.f,0.f,0.f,0.f};

    bf16x8 aH[4], aL[4];                                 // A frags (per kt)
    bf16x8 bsA[4], bsB[4], bsC[4];                       // per-gate B sets

    // ---- prologue: B g0(0) -> setA; A(0) -> buf0 --------------------------
    LOADB_SET(A, 0, 0);
    GLD16(Ah + gA, smem + wbB);
    GLD16(Al + gA, smem + 8192 + wbB);

    KT_BODY(0, 0, 0);
    #pragma unroll 1
    for (int kt2 = 0; kt2 < 11; ++kt2){
        KT_BODY(2*kt2+1, 1, 8);
        KT_BODY(2*kt2+2, 0, 8);
    }

    // ---- peeled kt=23 (P=1): no GLD16, no setA' ---------------------------
    {
        VMCNT(4); BARRIER();                 // <=4 outstanding => A(23) landed
        READ_A(smem + 16384);
        LOADB_SET(B, 1, 23);
        MFMA_CLUSTER(0, A);
        LOADB_SET(C, 2, 23);
        MFMA_CLUSTER(1, B);
        MFMA_CLUSTER(2, C);
    }

    // ---- epilogue: gates -> h -> partial feats ----------------------------
    int jcol[2];
    #pragma unroll
    for (int f=0; f<2; ++f) jcol[f] = j0 + wn*32 + f*16 + lm;   // 0..255

    float bi[2], bg_[2], bo[2];
    #pragma unroll
    for (int f=0; f<2; ++f){
        bi[f]  = bih[jcol[f]]       + bhh[jcol[f]];
        bg_[f] = bih[512 + jcol[f]] + bhh[512 + jcol[f]];
        bo[f]  = bih[768 + jcol[f]] + bhh[768 + jcol[f]];
    }
    float hv[4][2][4];
    #pragma unroll
    for (int fm=0; fm<4; ++fm)
        #pragma unroll
        for (int fn=0; fn<2; ++fn)
            #pragma unroll
            for (int r=0; r<4; ++r){
                float cv = sigm(acc[0][fm][fn][r] + bi[fn]) *
                           tanhf(acc[1][fm][fn][r] + bg_[fn]);
                hv[fm][fn][r] = sigm(acc[2][fm][fn][r] + bo[fn]) * tanhf(cv);
            }

    __syncthreads();   // all K-loop LDS reads done before smem reuse
    // wts[cc][t][j]: wtag slice for the two 64-col chunks of this block
    for (int idx=tid; idx<2*NT*64; idx+=512){
        int cc = idx / (NT*64), r = idx - cc*(NT*64);
        int t = r >> 6, j = r & 63;
        wts[idx] = wtag[t*HIDD + dir*256 + j0 + cc*64 + j];
    }
    #pragma unroll 1
    for (int cc=0; cc<2; ++cc){
        __syncthreads();
        if ((wn >> 1) == cc){
            #pragma unroll
            for (int fm=0; fm<4; ++fm)
                #pragma unroll
                for (int fn=0; fn<2; ++fn)
                    #pragma unroll
                    for (int r=0; r<4; ++r){
                        int mloc = wm*64 + fm*16 + lq*4 + r;    // 0..127
                        int jloc = (wn&1)*32 + fn*16 + lm;      // 0..63
                        hbuf[mloc*65 + jloc] = hv[fm][fn][r];
                    }
        }
        __syncthreads();
        // same 64-long fmaf chain per (row, chunk, tag) as prior rounds
        const int mrow = tid & 127, grp = tid >> 7;             // 4 grp x 5 tags
        const int tg0 = grp*5;
        const float* wc = wts + cc*(NT*64);
        float s[5] = {0.f,0.f,0.f,0.f,0.f};
        for (int j=0;j<64;++j){
            float h = hbuf[mrow*65 + j];
            #pragma unroll
            for (int tt=0; tt<5; ++tt)
                s[tt] = fmaf(h, wc[(tg0+tt)*64 + j], s[tt]);
        }
        const int p = dir*4 + jhalf*2 + cc;                     // partial idx
        float* fq = featsp + (size_t)p * (NTOK*NT);
        const int mglob = row0 + mrow;
        #pragma unroll
        for (int tt=0; tt<5; ++tt)
            fq[(size_t)mglob*NT + tg0 + tt] = s[tt];
    }
}

// ---------------------------------------------------------------------------
// fl loader: identical deterministic sum of the 8 partial buffers + btag.
// ---------------------------------------------------------------------------
__device__ __forceinline__ void load_fl(
    const float* __restrict__ featsp, const float* __restrict__ btg,
    float* fl, int c, int tid, int nthr)
{
    const int base = c*(CLEN*NT/4);
    for (int idx=tid; idx<CLEN*NT/4; idx+=nthr){
        float4 s[8];
        #pragma unroll
        for (int p=0; p<8; ++p)
            s[p] = ((const float4*)(featsp + (size_t)p*NTOK*NT))[base+idx];
        float4 v;
        v.x = ((s[0].x+s[1].x)+(s[2].x+s[3].x)) + ((s[4].x+s[5].x)+(s[6].x+s[7].x));
        v.y = ((s[0].y+s[1].y)+(s[2].y+s[3].y)) + ((s[4].y+s[5].y)+(s[6].y+s[7].y));
        v.z = ((s[0].z+s[1].z)+(s[2].z+s[3].z)) + ((s[4].z+s[5].z)+(s[6].z+s[7].z));
        v.w = ((s[0].w+s[1].w)+(s[2].w+s[3].w)) + ((s[4].w+s[5].w)+(s[6].w+s[7].w));
        int t0 = (idx*4) % 20;
        v.x += btg[t0]; v.y += btg[t0+1]; v.z += btg[t0+2]; v.w += btg[t0+3];
        ((float4*)fl)[idx] = v;
    }
}

// ---------------------------------------------------------------------------
// V1 (R6 layout kept): per-chunk max-plus matrix product, transposed LDS
// (Pt[j][k], stride 24) -> column read = 5x ds_read_b128; thread = (j, row
// pair). Arithmetic bit-identical to the original.
// ---------------------------------------------------------------------------
__global__ __launch_bounds__(256) void vit_chunkmat(
    const float* __restrict__ featsp, const float* __restrict__ btag,
    const float* __restrict__ trans, float* __restrict__ Pall)
{
    __shared__ float fl[CLEN*NT];
    __shared__ float Pt[2][NT*24];          // transposed, padded stride 24
    const int c = blockIdx.x, tid = threadIdx.x;
    load_fl(featsp, btag, fl, c, tid, 256);
    const bool act = tid < 200;
    const int j = tid / 10, ip = tid - j*10;
    const int ia = ip*2, ib = ia + 1;
    float tra[NT], trb[NT];
    if (act){
        #pragma unroll
        for (int k=0;k<NT;++k){
            tra[k] = trans[ia*NT+k];
            trb[k] = trans[ib*NT+k];
        }
        Pt[0][j*24+ia] = (ia==j) ? 0.f : -1e30f;
        Pt[0][j*24+ib] = (ib==j) ? 0.f : -1e30f;
    }
    __syncthreads();
    int cur = 0;
    #pragma unroll 1
    for (int t=0;t<CLEN;++t){
        if (act){
            float p[NT];
            #pragma unroll
            for (int q=0;q<5;++q){
                float4 v = *(const float4*)&Pt[cur][j*24 + q*4];
                p[q*4+0]=v.x; p[q*4+1]=v.y; p[q*4+2]=v.z; p[q*4+3]=v.w;
            }
            float ma = -3.0e38f, mb = -3.0e38f;
            #pragma unroll
            for (int k=0;k<NT;++k){
                ma = fmaxf(ma, tra[k] + p[k]);      // same chain order as before
                mb = fmaxf(mb, trb[k] + p[k]);
            }
            ma += fl[t*NT+ia];
            mb += fl[t*NT+ib];
            Pt[cur^1][j*24+ia] = ma;
            Pt[cur^1][j*24+ib] = mb;
        }
        __syncthreads();
        cur ^= 1;
    }
    if (act){
        Pall[(size_t)c*(NT*NT) + ia*NT + j] = Pt[cur][j*24+ia];
        Pall[(size_t)c*(NT*NT) + ib*NT + j] = Pt[cur][j*24+ib];
    }
}

// ---------------------------------------------------------------------------
// V2: sequential chunk scan -> fv at chunk starts + terminal argmax/score.
// ---------------------------------------------------------------------------
__global__ __launch_bounds__(128) void vit_scan(
    const float* __restrict__ Pall, const float* __restrict__ trans,
    float* __restrict__ fvstart, float* __restrict__ dout, int* __restrict__ bestws)
{
    __shared__ float Pb[NT*NT];
    __shared__ float fv[NT];
    const int tid = threadIdx.x;
    float4 pn = {0.f,0.f,0.f,0.f};
    if (tid<100) pn = ((const float4*)Pall)[tid];
    if (tid<NT) fv[tid] = (tid==18) ? 0.f : -10000.f;   // START=18
    for (int c=0;c<CHUNKS;++c){
        if (tid<100) ((float4*)Pb)[tid] = pn;
        if (tid<100 && c+1<CHUNKS) pn = ((const float4*)(Pall + (size_t)(c+1)*(NT*NT)))[tid];
        __syncthreads();
        if (tid<NT) fvstart[c*NT+tid] = fv[tid];
        float nf = -3.0e38f;
        if (tid<NT){
            #pragma unroll
            for (int j=0;j<NT;++j) nf = fmaxf(nf, Pb[tid*NT+j] + fv[j]);
        }
        __syncthreads();
        if (tid<NT) fv[tid] = nf;
    }
    __syncthreads();
    if (tid==0){
        float best = -3.0e38f; int bidx = 0;
        for (int j=0;j<NT;++j){
            float tv = fv[j] + trans[19*NT+j];          // STOP row = 19
            if (tv > best){ best = tv; bidx = j; }
        }
        dout[0] = best;
        bestws[0] = bidx;
    }
}

// ---------------------------------------------------------------------------
// V3: exact per-step replay (reference argmax semantics) -> backpointers + H_c
// ---------------------------------------------------------------------------
__global__ __launch_bounds__(128) void vit_replay(
    const float* __restrict__ featsp, const float* __restrict__ btag,
    const float* __restrict__ trans, const float* __restrict__ fvstart,
    unsigned int* __restrict__ bpout, int* __restrict__ Hout)
{
    __shared__ float fl[CLEN*NT];
    __shared__ float fv[NT];
    __shared__ unsigned char bp[CLEN*NT];
    const int c = blockIdx.x, tid = threadIdx.x;
    load_fl(featsp, btag, fl, c, tid, 128);
    float tr[NT];
    if (tid<NT){
        fv[tid] = fvstart[c*NT+tid];
        #pragma unroll
        for (int k=0;k<NT;++k) tr[k] = trans[tid*NT+k];
    }
    __syncthreads();
    for (int t=0;t<CLEN;++t){
        float best = 0.f; int bj = 0;
        if (tid<NT){
            best = tr[0] + fv[0];
            #pragma unroll
            for (int j=1;j<NT;++j){
                float v = tr[j] + fv[j];
                if (v > best){ best = v; bj = j; }      // strict > == first-win
            }
        }
        __syncthreads();
        if (tid<NT){
            fv[tid] = best + fl[t*NT+tid];
            bp[t*NT+tid] = (unsigned char)bj;
        }
        __syncthreads();
    }
    for (int idx=tid; idx<CLEN*NT/4; idx+=128)
        bpout[(size_t)c*(CLEN*NT/4) + idx] = ((unsigned int*)bp)[idx];
    if (tid<NT){
        int m = tid;
        for (int t=CLEN-1;t>=0;--t) m = bp[t*NT+m];
        Hout[c*NT+tid] = m;
    }
}

// ---------------------------------------------------------------------------
// V4: each block walks the composed chunk maps from bestws down to its own
// chunk, then backtracks its chunk and writes the path slice.
// ---------------------------------------------------------------------------
__global__ __launch_bounds__(64) void bt_fill(
    const unsigned int* __restrict__ bpin, const int* __restrict__ Hin,
    const int* __restrict__ bestws, float* __restrict__ dout)
{
    __shared__ int Hl[CHUNKS*NT];
    __shared__ unsigned char bp[CLEN*NT];
    __shared__ float ob[CLEN];
    const int c = blockIdx.x, tid = threadIdx.x;
    for (int idx=tid; idx<CHUNKS*NT; idx+=64) Hl[idx] = Hin[idx];
    for (int idx=tid; idx<CLEN*NT/4; idx+=64)
        ((unsigned int*)bp)[idx] = bpin[(size_t)c*(CLEN*NT/4) + idx];
    __syncthreads();
    if (tid==0){
        int e = bestws[0];
        for (int cc=CHUNKS-1; cc>c; --cc) e = Hl[cc*NT+e];
        for (int t=CLEN-1;t>=0;--t){ ob[t] = (float)e; e = bp[t*NT+e]; }
    }
    __syncthreads();
    for (int idx=tid; idx<CLEN; idx+=64)
        dout[1 + c*CLEN + idx] = ob[idx];
}

// ---------------------------------------------------------------------------
extern "C" void kernel_launch(void* const* d_in, const int* in_sizes, int n_in,
                              void* d_out, int out_size, void* d_ws, size_t ws_size,
                              hipStream_t stream)
{
    const float* x    = (const float*)d_in[0];
    const float* wf   = (const float*)d_in[1];
    const float* bihf = (const float*)d_in[3];
    const float* bhhf = (const float*)d_in[4];
    const float* wb   = (const float*)d_in[5];
    const float* bihb = (const float*)d_in[7];
    const float* bhhb = (const float*)d_in[8];
    const float* wtag = (const float*)d_in[9];
    const float* btag = (const float*)d_in[10];
    const float* trans= (const float*)d_in[11];
    float* out = (float*)d_out;

    char* w = (char*)d_ws;
    ushort_t* Ah = (ushort_t*)w;         w += 25165824;   // 16384*768*2
    ushort_t* Al = (ushort_t*)w;         w += 25165824;
    ushort_t* Bh = (ushort_t*)w;         w += 2359296;    // 1536*768*2
    ushort_t* Bl = (ushort_t*)w;         w += 2359296;
    float* featsp = (float*)w;           w += 10485760;   // 8 * 16384*20 * 4B
    float* Pall  = (float*)w;            w += 204800;     // 128*400*4
    float* fvst  = (float*)w;            w += 10240;      // 128*20*4
    int* Hmap    = (int*)w;              w += 10240;      // 128*20*4
    unsigned int* bp = (unsigned int*)w; w += 327680;     // 16384*20 bytes
    int* best    = (int*)w;

    conv_kernel<<<13440, 256, 0, stream>>>(x, wf, wb, Ah, Al, Bh, Bl);
    gemm_fused<<<512, 512, 0, stream>>>(Ah, Al, Bh, Bl, bihf, bhhf, bihb, bhhb,
                                        wtag, featsp);
    vit_chunkmat<<<CHUNKS, 256, 0, stream>>>(featsp, btag, trans, Pall);
    vit_scan<<<1, 128, 0, stream>>>(Pall, trans, fvst, out, best);
    vit_replay<<<CHUNKS, 128, 0, stream>>>(featsp, btag, trans, fvst, bp, Hmap);
    bt_fill<<<CHUNKS, 64, 0, stream>>>(bp, Hmap, best, out);
}

// Round 9
// 376.578 us; speedup vs baseline: 1.3359x; 1.1382x over previous
//
#include <hip/hip_runtime.h>
#include <math.h>

#define HDIM 768
#define HIDD 512
#define NTOK 16384
#define NT 20
#define CHUNKS 128
#define CLEN 128

typedef unsigned short ushort_t;
typedef __attribute__((ext_vector_type(8))) short bf16x8;
typedef __attribute__((ext_vector_type(4))) float f32x4;

__device__ __forceinline__ float sigm(float x){ return 1.0f/(1.0f+expf(-x)); }

__device__ __forceinline__ ushort_t f2bf(float f){
    unsigned int u = __float_as_uint(f);
    unsigned int r = (u + 0x7fffu + ((u >> 16) & 1u)) >> 16;
    return (ushort_t)r;
}
__device__ __forceinline__ float bf2f(ushort_t b){
    return __uint_as_float(((unsigned int)b) << 16);
}

#define GLD16(gp, lp) __builtin_amdgcn_global_load_lds( \
    (const __attribute__((address_space(1))) void*)(gp), \
    (__attribute__((address_space(3))) void*)(lp), 16, 0, 0)

// ---------------------------------------------------------------------------
// conv: blocks [0,1152) pack B (w_ih f/b gates i,g,o) into MFMA-FRAGMENT-
// LINEAR layout B'[cg][kt][lane][16B] (cg=n>>4, lane=lq*16+lm) so gemm's
// per-lane B loads are fully coalesced (R9). Values identical to R8 (same
// (wrow,c4) reads, same f2bf split) -- only the address permutes.
// Blocks [1152,13440): x rows 1..16384 -> Ah/Al (16384x768), unchanged.
// ---------------------------------------------------------------------------
__global__ __launch_bounds__(256) void conv_kernel(
    const float* __restrict__ x,
    const float* __restrict__ wf, const float* __restrict__ wb,
    ushort_t* __restrict__ Ah, ushort_t* __restrict__ Al,
    ushort_t* __restrict__ Bh, ushort_t* __restrict__ Bl)
{
    const int bid = blockIdx.x;
    if (bid < 1152){
        int t = bid*256 + threadIdx.x;                 // 1536*192
        int n = t / 192, c4 = (t - n*192)*4;
        int dir = n / 768, nr = n - dir*768;
        int gate = nr >> 8, j = nr & 255;
        int wrow = j + ((gate==0)?0:((gate==1)?512:768));
        const float* src = dir ? wb : wf;
        const float4 v = *(const float4*)(src + (size_t)wrow*HDIM + c4);
        float f[4] = {v.x, v.y, v.z, v.w};
        ushort_t h[4], l[4];
        #pragma unroll
        for (int i=0;i<4;++i){
            h[i] = f2bf(f[i]);
            l[i] = f2bf(f[i] - bf2f(h[i]));
        }
        // fragment-linear address for element (n, k=c4+i):
        //   cg=n>>4, lm=n&15, kt=k>>5, lq=(k&31)>>3, ke=k&7
        int cg = n >> 4, lm = n & 15;
        int kt = c4 >> 5, lq = (c4 & 31) >> 3, ke = c4 & 7;   // ke in {0,4}
        size_t off = (size_t)cg*24576 + kt*1024 + (lq*16 + lm)*16 + ke*2;
        *(ushort4*)((char*)Bh + off) = make_ushort4(h[0],h[1],h[2],h[3]);
        *(ushort4*)((char*)Bl + off) = make_ushort4(l[0],l[1],l[2],l[3]);
    } else {
        int t = (bid-1152)*256 + threadIdx.x;          // 16384*192
        int row = t / 192, c4 = (t - row*192)*4;
        const float4 v = *(const float4*)(x + (size_t)(row+1)*HDIM + c4);
        float f[4] = {v.x, v.y, v.z, v.w};
        ushort_t h[4], l[4];
        #pragma unroll
        for (int i=0;i<4;++i){
            h[i] = f2bf(f[i]);
            l[i] = f2bf(f[i] - bf2f(h[i]));
        }
        *(ushort4*)(Ah + (size_t)row*HDIM + c4) = make_ushort4(h[0],h[1],h[2],h[3]);
        *(ushort4*)(Al + (size_t)row*HDIM + c4) = make_ushort4(l[0],l[1],l[2],l[3]);
    }
}

// ---------------------------------------------------------------------------
// Split-bf16 MFMA GEMM, R9: B direct-to-register with COALESCED fragment
// loads. R8 proved no-spill but regressed (199 us, MfmaUtil 24.5): per-lane
// B addresses were row-strided (16 cache lines per wave-load, ~16x
// transaction amplification). R9 keeps R8's schedule byte-for-byte and only
// changes B addressing to the fragment-linear layout written by conv:
// wave-load = base + lane*16 -> one contiguous 1024-B burst per instr.
// Per-kt/CU: MFMA 2794 cyc || LDS(A) ~830 || B-VMEM ~700 (L1/L2-served) --
// side-pipes below MFMA for the first time.
//   issue order per kt: setB=g1(kt)[4], GLD16 A(kt+1)[2], setC=g2(kt)[4],
//                       setA=g0(kt+1)[4]; each set covered by >=1 ~930-cyc
//                       MFMA cluster before use.
//   kt-top VMCNT(8): in-order vmcnt retirement => GLD16(A(kt)) certified
//   (actual outstanding at top <= 4). kt=0: VMCNT(0); tail: VMCNT(4).
// B values identical, per-acc MFMA order (kt 0..23; hh,lh,hl) identical,
// epilogue identical -> bit-identical gates/feats.
// Tripwire: WRITE_SIZE >~ 12 MB = spill -> revert to R6 gemm.
// ---------------------------------------------------------------------------
#define VMCNT(n) asm volatile("s_waitcnt vmcnt(" #n ")" ::: "memory")
#define BARRIER() asm volatile("s_barrier" ::: "memory")

#define LOADB_SET(S, g, KT) do{                                               \
    bs##S[0] = *(const bf16x8*)((const char*)Bh + bByte[g][0] + (KT)*1024);   \
    bs##S[1] = *(const bf16x8*)((const char*)Bl + bByte[g][0] + (KT)*1024);   \
    bs##S[2] = *(const bf16x8*)((const char*)Bh + bByte[g][1] + (KT)*1024);   \
    bs##S[3] = *(const bf16x8*)((const char*)Bl + bByte[g][1] + (KT)*1024);   \
}while(0)

#define READ_A(ab) do{ _Pragma("unroll") for (int f=0; f<4; ++f){             \
    aH[f] = *(const bf16x8*)((ab) + aoffB[f]);                                \
    aL[f] = *(const bf16x8*)((ab) + 8192 + aoffB[f]); } }while(0)

// per-acc order (hh, lh, hl) identical to prior rounds -> bit-exact
#define MFMA_CLUSTER(g, S) do{                                                \
  __builtin_amdgcn_sched_barrier(0);                                          \
  __builtin_amdgcn_s_setprio(1);                                              \
  _Pragma("unroll")                                                           \
  for (int fn=0; fn<2; ++fn){                                                 \
    _Pragma("unroll")                                                         \
    for (int fm=0; fm<4; ++fm){                                               \
      acc[g][fm][fn] = __builtin_amdgcn_mfma_f32_16x16x32_bf16(aH[fm],        \
          bs##S[fn*2], acc[g][fm][fn], 0, 0, 0);                              \
      acc[g][fm][fn] = __builtin_amdgcn_mfma_f32_16x16x32_bf16(aL[fm],        \
          bs##S[fn*2], acc[g][fm][fn], 0, 0, 0);                              \
      acc[g][fm][fn] = __builtin_amdgcn_mfma_f32_16x16x32_bf16(aH[fm],        \
          bs##S[fn*2+1], acc[g][fm][fn], 0, 0, 0);                            \
    }                                                                         \
  }                                                                           \
  __builtin_amdgcn_s_setprio(0);                                              \
  __builtin_amdgcn_sched_barrier(0);                                          \
}while(0)

// P = kt parity (LDS buf); VM = kt-top vmcnt
#define KT_BODY(KT, P, VM) do{                                                \
    VMCNT(VM); BARRIER();                                                     \
    READ_A(smem + (P)*16384);                                                 \
    LOADB_SET(B, 1, KT);                                                      \
    GLD16(Ah + gA + ((KT)+1)*32, smem + (1-(P))*16384 + wbB);                 \
    GLD16(Al + gA + ((KT)+1)*32, smem + (1-(P))*16384 + 8192 + wbB);          \
    MFMA_CLUSTER(0, A);                                                       \
    LOADB_SET(C, 2, KT);                                                      \
    MFMA_CLUSTER(1, B);                                                       \
    LOADB_SET(A, 0, (KT)+1);                                                  \
    MFMA_CLUSTER(2, C);                                                       \
}while(0)

__global__ __launch_bounds__(512, 1) void gemm_fused(
    const ushort_t* __restrict__ Ah, const ushort_t* __restrict__ Al,
    const ushort_t* __restrict__ Bh, const ushort_t* __restrict__ Bl,
    const float* __restrict__ bihf, const float* __restrict__ bhhf,
    const float* __restrict__ bihb, const float* __restrict__ bhhb,
    const float* __restrict__ wtag, float* __restrict__ featsp)
{
    __shared__ __align__(16) char smem[43520];
    // loop: A buf P at P*16384 (Ah 8K @0, Al 8K @8192), dbuf = 32 KB.
    // epilogue reuse: hbuf 128x65 f32 @0, wts 2x20x64 f32 @33280.
    float* hbuf = (float*)smem;
    float* wts  = (float*)(smem + 33280);

    const int tid = threadIdx.x;
    const int bx = blockIdx.x;
    const int xcd = bx & 7, g3 = bx >> 3;
    const int qb = g3 & 3, mt = (g3 >> 2)*8 + xcd;       // 4 qb share XCD
    const int dir = qb >> 1, jhalf = qb & 1;
    const int j0 = jhalf*128;
    const int row0 = mt*128;
    const float* __restrict__ bih = dir ? bihb : bihf;
    const float* __restrict__ bhh = dir ? bhhb : bhhf;

    const int lane = tid & 63, wv = tid >> 6;            // 8 waves
    const int wm = wv >> 2, wn = wv & 3;                 // 2m x 4n
    const int lm = lane & 15, lq = lane >> 4;
    const int wbB = (tid & 448) * 16;                    // wave-uniform byte base

    // ---- A staging decode: slot tid -> (row 0..127, k8) under pair swizzle
    const int P_ = tid >> 3, s_ = tid & 7;
    const int q_ = s_ ^ (P_ & 7);
    const int mA = (P_ << 1) | (q_ >> 2);                // 0..127
    const int k8s = q_ & 3;
    const size_t gA  = (size_t)(row0 + mA)*HDIM + k8s*8;

    // ---- A fragment ds_read byte offsets ----------------------------------
    int aoffB[4];
    #pragma unroll
    for (int f=0; f<4; ++f){
        int m = wm*64 + f*16 + lm;                       // 0..127
        int rg = m >> 6, r = m & 63;
        aoffB[f] = rg*4096 + ((r>>1)*8 + ((((r&1)<<2)|lq) ^ ((r>>1)&7)))*16;
    }

    // ---- B fragment-linear byte bases: cg*24576 + lane*16 (+kt*1024) ------
    int bByte[3][2];
    #pragma unroll
    for (int g=0; g<3; ++g)
        #pragma unroll
        for (int f=0; f<2; ++f){
            int cg = dir*48 + g*16 + jhalf*8 + wn*2 + f; // colgroup 0..95
            bByte[g][f] = cg*24576 + lane*16;
        }

    f32x4 acc[3][4][2];                                  // [gate][fm][fn]
    #pragma unroll
    for (int g=0; g<3; ++g)
        #pragma unroll
        for (int fm=0; fm<4; ++fm)
            #pragma unroll
            for (int fn=0; fn<2; ++fn)
                acc[g][fm][fn] = (f32x4){0.f,0.f,0.f,0.f};

    bf16x8 aH[4], aL[4];                                 // A frags (per kt)
    bf16x8 bsA[4], bsB[4], bsC[4];                       // per-gate B sets

    // ---- prologue: B g0(0) -> setA; A(0) -> buf0 --------------------------
    LOADB_SET(A, 0, 0);
    GLD16(Ah + gA, smem + wbB);
    GLD16(Al + gA, smem + 8192 + wbB);

    KT_BODY(0, 0, 0);
    #pragma unroll 1
    for (int kt2 = 0; kt2 < 11; ++kt2){
        KT_BODY(2*kt2+1, 1, 8);
        KT_BODY(2*kt2+2, 0, 8);
    }

    // ---- peeled kt=23 (P=1): no GLD16, no setA' ---------------------------
    {
        VMCNT(4); BARRIER();                 // <=4 outstanding => A(23) landed
        READ_A(smem + 16384);
        LOADB_SET(B, 1, 23);
        MFMA_CLUSTER(0, A);
        LOADB_SET(C, 2, 23);
        MFMA_CLUSTER(1, B);
        MFMA_CLUSTER(2, C);
    }

    // ---- epilogue: gates -> h -> partial feats ----------------------------
    int jcol[2];
    #pragma unroll
    for (int f=0; f<2; ++f) jcol[f] = j0 + wn*32 + f*16 + lm;   // 0..255

    float bi[2], bg_[2], bo[2];
    #pragma unroll
    for (int f=0; f<2; ++f){
        bi[f]  = bih[jcol[f]]       + bhh[jcol[f]];
        bg_[f] = bih[512 + jcol[f]] + bhh[512 + jcol[f]];
        bo[f]  = bih[768 + jcol[f]] + bhh[768 + jcol[f]];
    }
    float hv[4][2][4];
    #pragma unroll
    for (int fm=0; fm<4; ++fm)
        #pragma unroll
        for (int fn=0; fn<2; ++fn)
            #pragma unroll
            for (int r=0; r<4; ++r){
                float cv = sigm(acc[0][fm][fn][r] + bi[fn]) *
                           tanhf(acc[1][fm][fn][r] + bg_[fn]);
                hv[fm][fn][r] = sigm(acc[2][fm][fn][r] + bo[fn]) * tanhf(cv);
            }

    __syncthreads();   // all K-loop LDS reads done before smem reuse
    // wts[cc][t][j]: wtag slice for the two 64-col chunks of this block
    for (int idx=tid; idx<2*NT*64; idx+=512){
        int cc = idx / (NT*64), r = idx - cc*(NT*64);
        int t = r >> 6, j = r & 63;
        wts[idx] = wtag[t*HIDD + dir*256 + j0 + cc*64 + j];
    }
    #pragma unroll 1
    for (int cc=0; cc<2; ++cc){
        __syncthreads();
        if ((wn >> 1) == cc){
            #pragma unroll
            for (int fm=0; fm<4; ++fm)
                #pragma unroll
                for (int fn=0; fn<2; ++fn)
                    #pragma unroll
                    for (int r=0; r<4; ++r){
                        int mloc = wm*64 + fm*16 + lq*4 + r;    // 0..127
                        int jloc = (wn&1)*32 + fn*16 + lm;      // 0..63
                        hbuf[mloc*65 + jloc] = hv[fm][fn][r];
                    }
        }
        __syncthreads();
        // same 64-long fmaf chain per (row, chunk, tag) as prior rounds
        const int mrow = tid & 127, grp = tid >> 7;             // 4 grp x 5 tags
        const int tg0 = grp*5;
        const float* wc = wts + cc*(NT*64);
        float s[5] = {0.f,0.f,0.f,0.f,0.f};
        for (int j=0;j<64;++j){
            float h = hbuf[mrow*65 + j];
            #pragma unroll
            for (int tt=0; tt<5; ++tt)
                s[tt] = fmaf(h, wc[(tg0+tt)*64 + j], s[tt]);
        }
        const int p = dir*4 + jhalf*2 + cc;                     // partial idx
        float* fq = featsp + (size_t)p * (NTOK*NT);
        const int mglob = row0 + mrow;
        #pragma unroll
        for (int tt=0; tt<5; ++tt)
            fq[(size_t)mglob*NT + tg0 + tt] = s[tt];
    }
}

// ---------------------------------------------------------------------------
// fl loader: identical deterministic sum of the 8 partial buffers + btag.
// ---------------------------------------------------------------------------
__device__ __forceinline__ void load_fl(
    const float* __restrict__ featsp, const float* __restrict__ btg,
    float* fl, int c, int tid, int nthr)
{
    const int base = c*(CLEN*NT/4);
    for (int idx=tid; idx<CLEN*NT/4; idx+=nthr){
        float4 s[8];
        #pragma unroll
        for (int p=0; p<8; ++p)
            s[p] = ((const float4*)(featsp + (size_t)p*NTOK*NT))[base+idx];
        float4 v;
        v.x = ((s[0].x+s[1].x)+(s[2].x+s[3].x)) + ((s[4].x+s[5].x)+(s[6].x+s[7].x));
        v.y = ((s[0].y+s[1].y)+(s[2].y+s[3].y)) + ((s[4].y+s[5].y)+(s[6].y+s[7].y));
        v.z = ((s[0].z+s[1].z)+(s[2].z+s[3].z)) + ((s[4].z+s[5].z)+(s[6].z+s[7].z));
        v.w = ((s[0].w+s[1].w)+(s[2].w+s[3].w)) + ((s[4].w+s[5].w)+(s[6].w+s[7].w));
        int t0 = (idx*4) % 20;
        v.x += btg[t0]; v.y += btg[t0+1]; v.z += btg[t0+2]; v.w += btg[t0+3];
        ((float4*)fl)[idx] = v;
    }
}

// ---------------------------------------------------------------------------
// V1 (R6 layout kept): per-chunk max-plus matrix product, transposed LDS
// (Pt[j][k], stride 24) -> column read = 5x ds_read_b128; thread = (j, row
// pair). Arithmetic bit-identical to the original.
// ---------------------------------------------------------------------------
__global__ __launch_bounds__(256) void vit_chunkmat(
    const float* __restrict__ featsp, const float* __restrict__ btag,
    const float* __restrict__ trans, float* __restrict__ Pall)
{
    __shared__ float fl[CLEN*NT];
    __shared__ float Pt[2][NT*24];          // transposed, padded stride 24
    const int c = blockIdx.x, tid = threadIdx.x;
    load_fl(featsp, btag, fl, c, tid, 256);
    const bool act = tid < 200;
    const int j = tid / 10, ip = tid - j*10;
    const int ia = ip*2, ib = ia + 1;
    float tra[NT], trb[NT];
    if (act){
        #pragma unroll
        for (int k=0;k<NT;++k){
            tra[k] = trans[ia*NT+k];
            trb[k] = trans[ib*NT+k];
        }
        Pt[0][j*24+ia] = (ia==j) ? 0.f : -1e30f;
        Pt[0][j*24+ib] = (ib==j) ? 0.f : -1e30f;
    }
    __syncthreads();
    int cur = 0;
    #pragma unroll 1
    for (int t=0;t<CLEN;++t){
        if (act){
            float p[NT];
            #pragma unroll
            for (int q=0;q<5;++q){
                float4 v = *(const float4*)&Pt[cur][j*24 + q*4];
                p[q*4+0]=v.x; p[q*4+1]=v.y; p[q*4+2]=v.z; p[q*4+3]=v.w;
            }
            float ma = -3.0e38f, mb = -3.0e38f;
            #pragma unroll
            for (int k=0;k<NT;++k){
                ma = fmaxf(ma, tra[k] + p[k]);      // same chain order as before
                mb = fmaxf(mb, trb[k] + p[k]);
            }
            ma += fl[t*NT+ia];
            mb += fl[t*NT+ib];
            Pt[cur^1][j*24+ia] = ma;
            Pt[cur^1][j*24+ib] = mb;
        }
        __syncthreads();
        cur ^= 1;
    }
    if (act){
        Pall[(size_t)c*(NT*NT) + ia*NT + j] = Pt[cur][j*24+ia];
        Pall[(size_t)c*(NT*NT) + ib*NT + j] = Pt[cur][j*24+ib];
    }
}

// ---------------------------------------------------------------------------
// V2: sequential chunk scan -> fv at chunk starts + terminal argmax/score.
// ---------------------------------------------------------------------------
__global__ __launch_bounds__(128) void vit_scan(
    const float* __restrict__ Pall, const float* __restrict__ trans,
    float* __restrict__ fvstart, float* __restrict__ dout, int* __restrict__ bestws)
{
    __shared__ float Pb[NT*NT];
    __shared__ float fv[NT];
    const int tid = threadIdx.x;
    float4 pn = {0.f,0.f,0.f,0.f};
    if (tid<100) pn = ((const float4*)Pall)[tid];
    if (tid<NT) fv[tid] = (tid==18) ? 0.f : -10000.f;   // START=18
    for (int c=0;c<CHUNKS;++c){
        if (tid<100) ((float4*)Pb)[tid] = pn;
        if (tid<100 && c+1<CHUNKS) pn = ((const float4*)(Pall + (size_t)(c+1)*(NT*NT)))[tid];
        __syncthreads();
        if (tid<NT) fvstart[c*NT+tid] = fv[tid];
        float nf = -3.0e38f;
        if (tid<NT){
            #pragma unroll
            for (int j=0;j<NT;++j) nf = fmaxf(nf, Pb[tid*NT+j] + fv[j]);
        }
        __syncthreads();
        if (tid<NT) fv[tid] = nf;
    }
    __syncthreads();
    if (tid==0){
        float best = -3.0e38f; int bidx = 0;
        for (int j=0;j<NT;++j){
            float tv = fv[j] + trans[19*NT+j];          // STOP row = 19
            if (tv > best){ best = tv; bidx = j; }
        }
        dout[0] = best;
        bestws[0] = bidx;
    }
}

// ---------------------------------------------------------------------------
// V3: exact per-step replay (reference argmax semantics) -> backpointers + H_c
// ---------------------------------------------------------------------------
__global__ __launch_bounds__(128) void vit_replay(
    const float* __restrict__ featsp, const float* __restrict__ btag,
    const float* __restrict__ trans, const float* __restrict__ fvstart,
    unsigned int* __restrict__ bpout, int* __restrict__ Hout)
{
    __shared__ float fl[CLEN*NT];
    __shared__ float fv[NT];
    __shared__ unsigned char bp[CLEN*NT];
    const int c = blockIdx.x, tid = threadIdx.x;
    load_fl(featsp, btag, fl, c, tid, 128);
    float tr[NT];
    if (tid<NT){
        fv[tid] = fvstart[c*NT+tid];
        #pragma unroll
        for (int k=0;k<NT;++k) tr[k] = trans[tid*NT+k];
    }
    __syncthreads();
    for (int t=0;t<CLEN;++t){
        float best = 0.f; int bj = 0;
        if (tid<NT){
            best = tr[0] + fv[0];
            #pragma unroll
            for (int j=1;j<NT;++j){
                float v = tr[j] + fv[j];
                if (v > best){ best = v; bj = j; }      // strict > == first-win
            }
        }
        __syncthreads();
        if (tid<NT){
            fv[tid] = best + fl[t*NT+tid];
            bp[t*NT+tid] = (unsigned char)bj;
        }
        __syncthreads();
    }
    for (int idx=tid; idx<CLEN*NT/4; idx+=128)
        bpout[(size_t)c*(CLEN*NT/4) + idx] = ((unsigned int*)bp)[idx];
    if (tid<NT){
        int m = tid;
        for (int t=CLEN-1;t>=0;--t) m = bp[t*NT+m];
        Hout[c*NT+tid] = m;
    }
}

// ---------------------------------------------------------------------------
// V4: each block walks the composed chunk maps from bestws down to its own
// chunk, then backtracks its chunk and writes the path slice.
// ---------------------------------------------------------------------------
__global__ __launch_bounds__(64) void bt_fill(
    const unsigned int* __restrict__ bpin, const int* __restrict__ Hin,
    const int* __restrict__ bestws, float* __restrict__ dout)
{
    __shared__ int Hl[CHUNKS*NT];
    __shared__ unsigned char bp[CLEN*NT];
    __shared__ float ob[CLEN];
    const int c = blockIdx.x, tid = threadIdx.x;
    for (int idx=tid; idx<CHUNKS*NT; idx+=64) Hl[idx] = Hin[idx];
    for (int idx=tid; idx<CLEN*NT/4; idx+=64)
        ((unsigned int*)bp)[idx] = bpin[(size_t)c*(CLEN*NT/4) + idx];
    __syncthreads();
    if (tid==0){
        int e = bestws[0];
        for (int cc=CHUNKS-1; cc>c; --cc) e = Hl[cc*NT+e];
        for (int t=CLEN-1;t>=0;--t){ ob[t] = (float)e; e = bp[t*NT+e]; }
    }
    __syncthreads();
    for (int idx=tid; idx<CLEN; idx+=64)
        dout[1 + c*CLEN + idx] = ob[idx];
}

// ---------------------------------------------------------------------------
extern "C" void kernel_launch(void* const* d_in, const int* in_sizes, int n_in,
                              void* d_out, int out_size, void* d_ws, size_t ws_size,
                              hipStream_t stream)
{
    const float* x    = (const float*)d_in[0];
    const float* wf   = (const float*)d_in[1];
    const float* bihf = (const float*)d_in[3];
    const float* bhhf = (const float*)d_in[4];
    const float* wb   = (const float*)d_in[5];
    const float* bihb = (const float*)d_in[7];
    const float* bhhb = (const float*)d_in[8];
    const float* wtag = (const float*)d_in[9];
    const float* btag = (const float*)d_in[10];
    const float* trans= (const float*)d_in[11];
    float* out = (float*)d_out;

    char* w = (char*)d_ws;
    ushort_t* Ah = (ushort_t*)w;         w += 25165824;   // 16384*768*2
    ushort_t* Al = (ushort_t*)w;         w += 25165824;
    ushort_t* Bh = (ushort_t*)w;         w += 2359296;    // frag-linear 96*24*64*16
    ushort_t* Bl = (ushort_t*)w;         w += 2359296;
    float* featsp = (float*)w;           w += 10485760;   // 8 * 16384*20 * 4B
    float* Pall  = (float*)w;            w += 204800;     // 128*400*4
    float* fvst  = (float*)w;            w += 10240;      // 128*20*4
    int* Hmap    = (int*)w;              w += 10240;      // 128*20*4
    unsigned int* bp = (unsigned int*)w; w += 327680;     // 16384*20 bytes
    int* best    = (int*)w;

    conv_kernel<<<13440, 256, 0, stream>>>(x, wf, wb, Ah, Al, Bh, Bl);
    gemm_fused<<<512, 512, 0, stream>>>(Ah, Al, Bh, Bl, bihf, bhhf, bihb, bhhb,
                                        wtag, featsp);
    vit_chunkmat<<<CHUNKS, 256, 0, stream>>>(featsp, btag, trans, Pall);
    vit_scan<<<1, 128, 0, stream>>>(Pall, trans, fvst, out, best);
    vit_replay<<<CHUNKS, 128, 0, stream>>>(featsp, btag, trans, fvst, bp, Hmap);
    bt_fill<<<CHUNKS, 64, 0, stream>>>(bp, Hmap, best, out);
}